// Round 1
// baseline (451.744 us; speedup 1.0000x reference)
//
#include <hip/hip_runtime.h>

// MHA forward: B=2, S=2048, HID=1024, NH=16, HD=64.
// Pipeline: cast/transpose prep -> 3 proj GEMMs (bf16 MFMA) -> flash attention -> out GEMM.
// All MFMA: f32_16x16x32_bf16. Layouts (m89/m91-verified):
//   A-frag: A[m=lane&15][k=(lane>>4)*8+j], contiguous K
//   B-frag: B[k=(lane>>4)*8+j][n=lane&15]  (read from B^T row-major, contiguous K)
//   C/D   : row=(lane>>4)*4+reg, col=lane&15

typedef unsigned short u16;
typedef __bf16 bf16x8 __attribute__((ext_vector_type(8)));
typedef float f32x4 __attribute__((ext_vector_type(4)));
typedef u16 u16x4 __attribute__((ext_vector_type(4)));

__device__ __forceinline__ u16 f2bf(float f) {
  union { float f; unsigned u; } x; x.f = f;
  unsigned r = (x.u + 0x7fffu + ((x.u >> 16) & 1u)) >> 16;  // RNE
  return (u16)r;
}

// ---------------- prep kernels ----------------

__global__ __launch_bounds__(256) void cast_kernel(const float* __restrict__ in,
                                                   u16* __restrict__ out, int n4) {
  int i = blockIdx.x * blockDim.x + threadIdx.x;
  if (i >= n4) return;
  float4 v = ((const float4*)in)[i];
  u16x4 o;
  o.x = f2bf(v.x); o.y = f2bf(v.y); o.z = f2bf(v.z); o.w = f2bf(v.w);
  ((u16x4*)out)[i] = o;
}

// WT[n][k] = bf16(W[k][n]); N fixed 1024
__global__ void transpose_cast(const float* __restrict__ W, u16* __restrict__ WT) {
  __shared__ float t[32][33];
  int bx = blockIdx.x * 32, by = blockIdx.y * 32;
  int tx = threadIdx.x, ty = threadIdx.y;  // block (32,8)
#pragma unroll
  for (int i = ty; i < 32; i += 8) t[i][tx] = W[(by + i) * 1024 + bx + tx];
  __syncthreads();
#pragma unroll
  for (int i = ty; i < 32; i += 8) WT[(bx + i) * 1024 + by + tx] = f2bf(t[tx][i]);
}

// ---------------- GEMM: C = A(bf16,[M,K]) * B + bias; BT is B^T (bf16,[N,K]) -------------
// mode 0: fp32 row-major -> Cf
// mode 1: bf16 -> Cb[((b*16+h)*2048+s)*64+d]   (row->(b,s), col->(h,d))
// mode 2: bf16 -> Cb[((b*16+h)*64+d)*2048+s]   (V transposed for PV B-frags)
__global__ __launch_bounds__(256) void gemm_bf16(
    const u16* __restrict__ A, const u16* __restrict__ BT,
    const float* __restrict__ bias,
    float* __restrict__ Cf, u16* __restrict__ Cb,
    int M, int N, int K, int mode) {
  __shared__ __align__(16) u16 As[128][72];
  __shared__ __align__(16) u16 Bs[128][72];
  int tid = threadIdx.x;
  int bm = blockIdx.y * 128, bn = blockIdx.x * 128;
  int w = tid >> 6, lane = tid & 63, quad = lane >> 4, l16 = lane & 15;
  int wr = (w >> 1) * 64, wc = (w & 1) * 64;
  f32x4 acc[4][4] = {};

  for (int k0 = 0; k0 < K; k0 += 64) {
    __syncthreads();
#pragma unroll
    for (int i = 0; i < 4; ++i) {
      int slot = tid + i * 256;
      int r = slot >> 3, c = (slot & 7) * 8;
      *(uint4*)&As[r][c] = *(const uint4*)&A[(size_t)(bm + r) * K + k0 + c];
      *(uint4*)&Bs[r][c] = *(const uint4*)&BT[(size_t)(bn + r) * K + k0 + c];
    }
    __syncthreads();
#pragma unroll
    for (int ks = 0; ks < 2; ++ks) {
      int kc = ks * 32 + quad * 8;
      bf16x8 af[4], bf[4];
#pragma unroll
      for (int mt = 0; mt < 4; ++mt) af[mt] = *(const bf16x8*)&As[wr + mt * 16 + l16][kc];
#pragma unroll
      for (int nt = 0; nt < 4; ++nt) bf[nt] = *(const bf16x8*)&Bs[wc + nt * 16 + l16][kc];
#pragma unroll
      for (int mt = 0; mt < 4; ++mt)
#pragma unroll
        for (int nt = 0; nt < 4; ++nt)
          acc[mt][nt] = __builtin_amdgcn_mfma_f32_16x16x32_bf16(af[mt], bf[nt], acc[mt][nt], 0, 0, 0);
    }
  }

#pragma unroll
  for (int mt = 0; mt < 4; ++mt)
#pragma unroll
    for (int nt = 0; nt < 4; ++nt)
#pragma unroll
      for (int r = 0; r < 4; ++r) {
        int row = bm + wr + mt * 16 + quad * 4 + r;
        int col = bn + wc + nt * 16 + l16;
        float v = acc[mt][nt][r] + bias[col];
        if (mode == 0) {
          Cf[(size_t)row * N + col] = v;
        } else {
          int b = row >> 11, s = row & 2047, h = col >> 6, d = col & 63;
          u16 bv = f2bf(v);
          if (mode == 1)
            Cb[(((size_t)(b * 16 + h) * 2048 + s) << 6) + d] = bv;
          else
            Cb[((size_t)(b * 16 + h) * 64 + d) * 2048 + s] = bv;
        }
      }
}

// ---------------- flash attention ----------------
// grid (16 qtiles, 16 heads, 2 batch), block 256 (4 waves x 32 query rows)
__global__ __launch_bounds__(256) void attn_kernel(
    const u16* __restrict__ Q,   // [B*NH, S, 64]
    const u16* __restrict__ Kk,  // [B*NH, S, 64]
    const u16* __restrict__ VT,  // [B*NH, 64, S]
    u16* __restrict__ ctx)       // [B*S, 1024]
{
  __shared__ __align__(16) u16 Ps[128][136];
  int qt = blockIdx.x, h = blockIdx.y, b = blockIdx.z;
  int bh = b * 16 + h;
  const u16* Qb = Q + ((size_t)bh * 2048 + qt * 128) * 64;
  const u16* Kb = Kk + (size_t)bh * 2048 * 64;
  const u16* Vb = VT + (size_t)bh * 64 * 2048;
  int tid = threadIdx.x, w = tid >> 6, lane = tid & 63, quad = lane >> 4, l16 = lane & 15;

  bf16x8 qf[2][2];
#pragma unroll
  for (int mt = 0; mt < 2; ++mt)
#pragma unroll
    for (int ks = 0; ks < 2; ++ks)
      qf[mt][ks] = *(const bf16x8*)&Qb[(w * 32 + mt * 16 + l16) * 64 + ks * 32 + quad * 8];

  f32x4 Oacc[2][4] = {};
  float m_old[2][4], l_old[2][4];
#pragma unroll
  for (int mt = 0; mt < 2; ++mt)
#pragma unroll
    for (int r = 0; r < 4; ++r) { m_old[mt][r] = -INFINITY; l_old[mt][r] = 0.f; }

  const float sc = 0.125f * 1.44269504f;  // 1/sqrt(64) * log2(e); softmax in base-2 domain

  for (int kv = 0; kv < 16; ++kv) {
    int kbase = kv * 128;
    f32x4 Sacc[2][8] = {};
#pragma unroll
    for (int nt = 0; nt < 8; ++nt) {
      int krow = kbase + nt * 16 + l16;
#pragma unroll
      for (int ks = 0; ks < 2; ++ks) {
        bf16x8 kfr = *(const bf16x8*)&Kb[(size_t)krow * 64 + ks * 32 + quad * 8];
#pragma unroll
        for (int mt = 0; mt < 2; ++mt)
          Sacc[mt][nt] = __builtin_amdgcn_mfma_f32_16x16x32_bf16(qf[mt][ks], kfr, Sacc[mt][nt], 0, 0, 0);
      }
    }
#pragma unroll
    for (int mt = 0; mt < 2; ++mt)
#pragma unroll
      for (int nt = 0; nt < 8; ++nt) Sacc[mt][nt] *= sc;

#pragma unroll
    for (int mt = 0; mt < 2; ++mt)
#pragma unroll
      for (int r = 0; r < 4; ++r) {
        float mx = Sacc[mt][0][r];
#pragma unroll
        for (int nt = 1; nt < 8; ++nt) mx = fmaxf(mx, Sacc[mt][nt][r]);
#pragma unroll
        for (int s = 1; s < 16; s <<= 1) mx = fmaxf(mx, __shfl_xor(mx, s, 64));
        float mn = fmaxf(m_old[mt][r], mx);
        float alpha = exp2f(m_old[mt][r] - mn);
        m_old[mt][r] = mn;
        float rs = 0.f;
#pragma unroll
        for (int nt = 0; nt < 8; ++nt) {
          float p = exp2f(Sacc[mt][nt][r] - mn);
          Sacc[mt][nt][r] = p;
          rs += p;
        }
#pragma unroll
        for (int s = 1; s < 16; s <<= 1) rs += __shfl_xor(rs, s, 64);
        l_old[mt][r] = alpha * l_old[mt][r] + rs;
#pragma unroll
        for (int dt = 0; dt < 4; ++dt) Oacc[mt][dt][r] *= alpha;
      }

    // P: C/D layout -> LDS -> A layout (each wave touches only its own 32 rows)
#pragma unroll
    for (int mt = 0; mt < 2; ++mt)
#pragma unroll
      for (int nt = 0; nt < 8; ++nt)
#pragma unroll
        for (int r = 0; r < 4; ++r)
          Ps[w * 32 + mt * 16 + quad * 4 + r][nt * 16 + l16] = f2bf(Sacc[mt][nt][r]);
    __syncthreads();

#pragma unroll
    for (int ks2 = 0; ks2 < 4; ++ks2) {
      int kc = ks2 * 32 + quad * 8;
      bf16x8 pf[2];
#pragma unroll
      for (int mt = 0; mt < 2; ++mt) pf[mt] = *(const bf16x8*)&Ps[w * 32 + mt * 16 + l16][kc];
#pragma unroll
      for (int dt = 0; dt < 4; ++dt) {
        bf16x8 vf = *(const bf16x8*)&Vb[(size_t)(dt * 16 + l16) * 2048 + kbase + kc];
#pragma unroll
        for (int mt = 0; mt < 2; ++mt)
          Oacc[mt][dt] = __builtin_amdgcn_mfma_f32_16x16x32_bf16(pf[mt], vf, Oacc[mt][dt], 0, 0, 0);
      }
    }
    __syncthreads();
  }

#pragma unroll
  for (int mt = 0; mt < 2; ++mt)
#pragma unroll
    for (int dt = 0; dt < 4; ++dt)
#pragma unroll
      for (int r = 0; r < 4; ++r) {
        int srow = qt * 128 + w * 32 + mt * 16 + quad * 4 + r;
        int d = dt * 16 + l16;
        float v = Oacc[mt][dt][r] / l_old[mt][r];
        ctx[(size_t)(b * 2048 + srow) * 1024 + h * 64 + d] = f2bf(v);
      }
}

// ---------------- launch ----------------

extern "C" void kernel_launch(void* const* d_in, const int* in_sizes, int n_in,
                              void* d_out, int out_size, void* d_ws, size_t ws_size,
                              hipStream_t stream) {
  const float* query = (const float*)d_in[0];
  const float* key_  = (const float*)d_in[1];
  const float* value = (const float*)d_in[2];
  const float* Wq = (const float*)d_in[3];
  const float* bq = (const float*)d_in[4];
  const float* Wk = (const float*)d_in[5];
  const float* bk = (const float*)d_in[6];
  const float* Wv = (const float*)d_in[7];
  const float* bv = (const float*)d_in[8];
  const float* Wo = (const float*)d_in[9];
  const float* bo = (const float*)d_in[10];
  float* out = (float*)d_out;

  char* ws = (char*)d_ws;
  const size_t MB = 1024 * 1024;
  u16* Aq  = (u16*)(ws + 0 * MB);    // 8 MB  bf16 query  [4096,1024]
  u16* Ak  = (u16*)(ws + 8 * MB);
  u16* Av  = (u16*)(ws + 16 * MB);
  u16* WqT = (u16*)(ws + 24 * MB);   // 2 MB each
  u16* WkT = (u16*)(ws + 26 * MB);
  u16* WvT = (u16*)(ws + 28 * MB);
  u16* WoT = (u16*)(ws + 30 * MB);
  u16* Qp  = (u16*)(ws + 32 * MB);   // 8 MB [B*NH, S, 64]
  u16* Kp  = (u16*)(ws + 40 * MB);
  u16* VTp = (u16*)(ws + 48 * MB);   // [B*NH, 64, S]
  u16* Ctx = (u16*)(ws + 56 * MB);   // 8 MB [4096, 1024]

  cast_kernel<<<4096, 256, 0, stream>>>(query, Aq, 1048576);
  cast_kernel<<<4096, 256, 0, stream>>>(key_, Ak, 1048576);
  cast_kernel<<<4096, 256, 0, stream>>>(value, Av, 1048576);

  dim3 tb(32, 8), tg(32, 32);
  transpose_cast<<<tg, tb, 0, stream>>>(Wq, WqT);
  transpose_cast<<<tg, tb, 0, stream>>>(Wk, WkT);
  transpose_cast<<<tg, tb, 0, stream>>>(Wv, WvT);
  transpose_cast<<<tg, tb, 0, stream>>>(Wo, WoT);

  dim3 gg(8, 32);
  gemm_bf16<<<gg, 256, 0, stream>>>(Aq, WqT, bq, nullptr, Qp, 4096, 1024, 1024, 1);
  gemm_bf16<<<gg, 256, 0, stream>>>(Ak, WkT, bk, nullptr, Kp, 4096, 1024, 1024, 1);
  gemm_bf16<<<gg, 256, 0, stream>>>(Av, WvT, bv, nullptr, VTp, 4096, 1024, 1024, 2);

  attn_kernel<<<dim3(16, 16, 2), 256, 0, stream>>>(Qp, Kp, VTp, Ctx);

  gemm_bf16<<<gg, 256, 0, stream>>>(Ctx, WoT, bo, out, nullptr, 4096, 1024, 1024, 0);
}